// Round 9
// baseline (1899.151 us; speedup 1.0000x reference)
//
#include <hip/hip_runtime.h>

#define TT  64
#define BSZ 512
#define ISZ 512
#define HSZ 1024

typedef short bf16x8 __attribute__((ext_vector_type(8)));
typedef float f32x4 __attribute__((ext_vector_type(4)));
typedef unsigned short u16x8 __attribute__((ext_vector_type(8)));

typedef const __attribute__((address_space(1))) unsigned int* gas_t;
typedef __attribute__((address_space(3))) unsigned int* las_t;

__device__ __forceinline__ unsigned short f2bf(float f) {
    unsigned int u = __float_as_uint(f);
    unsigned int r = u + 0x7FFFu + ((u >> 16) & 1u);   // RNE
    return (unsigned short)(r >> 16);
}

__global__ void cast_f32_to_bf16(const float* __restrict__ in,
                                 unsigned short* __restrict__ out, int n8) {
    int i = blockIdx.x * blockDim.x + threadIdx.x;
    if (i >= n8) return;
    const float4* p = (const float4*)(in + (size_t)i * 8);
    float4 v0 = p[0], v1 = p[1];
    u16x8 o;
    o[0] = f2bf(v0.x); o[1] = f2bf(v0.y); o[2] = f2bf(v0.z); o[3] = f2bf(v0.w);
    o[4] = f2bf(v1.x); o[5] = f2bf(v1.y); o[6] = f2bf(v1.z); o[7] = f2bf(v1.w);
    *(u16x8*)(out + (size_t)i * 8) = o;
}

__global__ void bias_combine(const float* __restrict__ a,
                             const float* __restrict__ b,
                             float* __restrict__ o) {
    int i = blockIdx.x * blockDim.x + threadIdx.x;
    if (i < 4 * HSZ) o[i] = a[i] + b[i];
}

__global__ void zero_arr(int* p, int n) {
    int i = blockIdx.x * blockDim.x + threadIdx.x;
    if (i < n) p[i] = 0;
}

// Persistent LSTM. 256 blocks (1/CU via 152KB LDS), 256 threads = 4 waves.
// Wave mg owns 32 b-rows, FULL K (no k-split -> no kreduce, no cross-wave
// barriers in the recurrent GEMM). W_hh slice (64x1024) LDS-resident.
// h A-operand staged via global_load_lds into a per-wave private 3-slot
// ring (deep queue, counted vmcnt, self-paced).
// h rotates through 64 per-step buffers [ni][512][16] (R7 scheme): no
// acquire fences; producer uses release-scope atomicAdd.
__global__ __launch_bounds__(256, 1) void lstm_persist(
    const unsigned short* __restrict__ xb,    // [TT, BSZ, ISZ] bf16
    const unsigned short* __restrict__ Wihb,  // [4096, 512]
    const unsigned short* __restrict__ Whhb,  // [4096, 1024]
    const float* __restrict__ bias,           // [4096]
    float* __restrict__ out,                  // fp32 output
    unsigned short* __restrict__ hbs,         // [TT][64][512][16] rotation
    int* __restrict__ arrive)
{
    __shared__ unsigned short WhL[64 * 1024];   // 128 KiB persistent W_hh
    __shared__ unsigned short AS[4 * 3 * 1024]; //  24 KiB A rings (4 waves x 3)

    const int tid  = threadIdx.x;
    const int lane = tid & 63;
    const int mg   = tid >> 6;       // wave = b-group (32 rows)
    const int lr   = lane & 15;
    const int kq   = lane >> 4;      // 0..3
    const int mi   = blockIdx.x >> 6;
    const int ni   = blockIdx.x & 63;
    const int b0   = mi * 128;
    const int hc0  = ni * 16;

    // ---- stage persistent W_hh slice (async). LDS[r][slot u] = G[r][u^(r&7)] ----
    #pragma unroll
    for (int i = 0; i < 32; ++i) {
        const int li = mg * 32 + i;            // 1KB unit, 0..127
        const int r = li >> 1, half = li & 1;
        const int grow = (r >> 4) * HSZ + hc0 + (r & 15);
        const int gslot = (half * 64 + lane) ^ (r & 7);
        const unsigned short* g = Whhb + (size_t)grow * HSZ + (size_t)gslot * 8;
        __builtin_amdgcn_global_load_lds((gas_t)g, (las_t)(WhL + li * 512), 16, 0, 0);
    }

    float bv[4];
    #pragma unroll
    for (int g = 0; g < 4; ++g) bv[g] = bias[g * HSZ + hc0 + lr];

    // ---- x-projection, full K=512, direct global (spin filler) ----
    auto x_part = [&](const unsigned short* xt, f32x4 (&acc)[2][4]) {
        #pragma unroll
        for (int m = 0; m < 2; ++m)
            #pragma unroll
            for (int g = 0; g < 4; ++g)
                acc[m][g] = (f32x4){bv[g], bv[g], bv[g], bv[g]};
        const unsigned short* xr = xt + (size_t)(b0 + mg * 32 + lr) * ISZ + kq * 8;
        const unsigned short* wr = Wihb + (size_t)(hc0 + lr) * ISZ + kq * 8;
        #pragma unroll
        for (int half = 0; half < 2; ++half) {
            bf16x8 ax[2][8];
            #pragma unroll
            for (int c = 0; c < 8; ++c) {
                ax[0][c] = *(const bf16x8*)(xr + half * 256 + c * 32);
                ax[1][c] = *(const bf16x8*)(xr + 16 * ISZ + half * 256 + c * 32);
            }
            #pragma unroll
            for (int c = 0; c < 8; ++c) {
                #pragma unroll
                for (int g = 0; g < 4; ++g) {
                    bf16x8 wf = *(const bf16x8*)(wr + (size_t)g * (HSZ * ISZ) + half * 256 + c * 32);
                    acc[0][g] = __builtin_amdgcn_mfma_f32_16x16x32_bf16(ax[0][c], wf, acc[0][g], 0, 0, 0);
                    acc[1][g] = __builtin_amdgcn_mfma_f32_16x16x32_bf16(ax[1][c], wf, acc[1][g], 0, 0, 0);
                }
            }
        }
    };

    // ---- stage A chunk c (32 rows x 32 cols) into ring slot (2 x gload_lds) ----
    // Source swizzled so read-side XOR lands correctly (rule-21 pair):
    // dest (row rl, 16B-slot s) holds global col-block c*4 + (s ^ (rl&3)).
    auto sth = [&](const unsigned short* hp, int c, int ring) {
        #pragma unroll
        for (int j = 0; j < 2; ++j) {
            const int rl = j * 16 + (lane >> 2);
            const int cb = c * 4 + ((lane & 3) ^ (rl & 3));
            const unsigned short* src = hp + (size_t)(cb >> 1) * 8192
                                        + (size_t)(b0 + mg * 32 + rl) * 16 + (cb & 1) * 8;
            __builtin_amdgcn_global_load_lds((gas_t)src,
                (las_t)(AS + (mg * 3 + ring) * 1024 + j * 512), 16, 0, 0);
        }
    };

    // ---- recurrent GEMM: acc += h_{t-1} @ Whh^T, self-paced ring ----
    auto h_gemm = [&](const unsigned short* hp, f32x4 (&acc)[2][4]) {
        sth(hp, 0, 0);
        sth(hp, 1, 1);
        int ring = 0;
        const int xa0 = ((kq ^ (lr & 3)) << 4);   // A swizzle (row&3 == lr&3 for both m)
        for (int c = 0; c < 32; ++c) {
            if (c < 31) asm volatile("s_waitcnt vmcnt(2)" ::: "memory");
            else        asm volatile("s_waitcnt vmcnt(0)" ::: "memory");
            __builtin_amdgcn_sched_barrier(0);
            const char* Ab = (const char*)(AS + (mg * 3 + ring) * 1024);
            bf16x8 a0 = *(const bf16x8*)(Ab + lr * 64 + xa0);
            bf16x8 a1 = *(const bf16x8*)(Ab + (16 + lr) * 64 + xa0);
            bf16x8 wf[4];
            const int slot = c * 4 + kq;
            const int woff = ((slot ^ (lr & 7)) << 4);
            #pragma unroll
            for (int g = 0; g < 4; ++g)
                wf[g] = *(const bf16x8*)((const char*)WhL + (g * 16 + lr) * 2048 + woff);
            asm volatile("s_waitcnt lgkmcnt(0)" ::: "memory");
            __builtin_amdgcn_sched_barrier(0);
            if (c + 2 < 32) {
                const int ring2 = (ring + 2) % 3;
                sth(hp, c + 2, ring2);
            }
            acc[0][0] = __builtin_amdgcn_mfma_f32_16x16x32_bf16(a0, wf[0], acc[0][0], 0, 0, 0);
            acc[1][0] = __builtin_amdgcn_mfma_f32_16x16x32_bf16(a1, wf[0], acc[1][0], 0, 0, 0);
            acc[0][1] = __builtin_amdgcn_mfma_f32_16x16x32_bf16(a0, wf[1], acc[0][1], 0, 0, 0);
            acc[1][1] = __builtin_amdgcn_mfma_f32_16x16x32_bf16(a1, wf[1], acc[1][1], 0, 0, 0);
            acc[0][2] = __builtin_amdgcn_mfma_f32_16x16x32_bf16(a0, wf[2], acc[0][2], 0, 0, 0);
            acc[1][2] = __builtin_amdgcn_mfma_f32_16x16x32_bf16(a1, wf[2], acc[1][2], 0, 0, 0);
            acc[0][3] = __builtin_amdgcn_mfma_f32_16x16x32_bf16(a0, wf[3], acc[0][3], 0, 0, 0);
            acc[1][3] = __builtin_amdgcn_mfma_f32_16x16x32_bf16(a1, wf[3], acc[1][3], 0, 0, 0);
            ring = (ring == 2) ? 0 : ring + 1;
        }
    };

    f32x4 acc[2][4];
    f32x4 creg[2];
    creg[0] = (f32x4){0.f, 0.f, 0.f, 0.f};
    creg[1] = (f32x4){0.f, 0.f, 0.f, 0.f};

    x_part(xb, acc);                                   // acc for t=0
    asm volatile("s_waitcnt vmcnt(0)" ::: "memory");   // W_hh staged
    __syncthreads();

    float* hn = out + (size_t)TT * BSZ * HSZ;
    float* cn = hn + (size_t)BSZ * HSZ;
    const int n = hc0 + lr;

    for (int t = 0; t < TT; ++t) {
        if (t > 0) h_gemm(hbs + (size_t)(t - 1) * 524288, acc);

        unsigned short* hslab = hbs + (size_t)t * 524288 + (size_t)ni * 8192;
        float* outt = out + (size_t)t * BSZ * HSZ;
        f32x4 hv[2];
        #pragma unroll
        for (int m = 0; m < 2; ++m) {
            #pragma unroll
            for (int r = 0; r < 4; ++r) {
                const int b = b0 + mg * 32 + m * 16 + kq * 4 + r;
                float gi = acc[m][0][r];
                float gf = acc[m][1][r];
                float gg = acc[m][2][r];
                float go = acc[m][3][r];
                float ig = 1.f / (1.f + __expf(-gi));
                float fg = 1.f / (1.f + __expf(-gf));
                float gv = 1.f - 2.f / (__expf(2.f * gg) + 1.f);
                float og = 1.f / (1.f + __expf(-go));
                float cnew = fg * creg[m][r] + ig * gv;
                float h = og * (1.f - 2.f / (__expf(2.f * cnew) + 1.f));
                creg[m][r] = cnew;
                hv[m][r] = h;
                hslab[(size_t)b * 16 + lr] = f2bf(h);
            }
        }

        if (t + 1 < TT) {
            __syncthreads();   // h-slab stores drained
            int* ctr = arrive + (size_t)t * 128 + mi * 32;
            if (tid == 0)
                __hip_atomic_fetch_add(ctr, 1, __ATOMIC_RELEASE, __HIP_MEMORY_SCOPE_AGENT);
            // deferred fp32 output stores + next x-projection as spin filler
            #pragma unroll
            for (int m = 0; m < 2; ++m)
                #pragma unroll
                for (int r = 0; r < 4; ++r) {
                    const int b = b0 + mg * 32 + m * 16 + kq * 4 + r;
                    outt[(size_t)b * HSZ + n] = hv[m][r];
                }
            x_part(xb + (size_t)(t + 1) * BSZ * ISZ, acc);
            if (tid == 0) {
                while (__hip_atomic_load(ctr, __ATOMIC_RELAXED, __HIP_MEMORY_SCOPE_AGENT) < 64)
                    __builtin_amdgcn_s_sleep(1);
            }
            __syncthreads();
        } else {
            #pragma unroll
            for (int m = 0; m < 2; ++m)
                #pragma unroll
                for (int r = 0; r < 4; ++r) {
                    const int b = b0 + mg * 32 + m * 16 + kq * 4 + r;
                    const size_t idx = (size_t)b * HSZ + n;
                    outt[idx] = hv[m][r];
                    hn[idx] = hv[m][r];
                    cn[idx] = creg[m][r];
                }
        }
    }
}

extern "C" void kernel_launch(void* const* d_in, const int* in_sizes, int n_in,
                              void* d_out, int out_size, void* d_ws, size_t ws_size,
                              hipStream_t stream) {
    const float* input_ = (const float*)d_in[0];
    const float* Wih = (const float*)d_in[3];
    const float* Whh = (const float*)d_in[4];
    const float* bih = (const float*)d_in[5];
    const float* bhh = (const float*)d_in[6];

    char* ws = (char*)d_ws;
    unsigned short* Wihb = (unsigned short*)(ws);                 //  4 MB
    unsigned short* Whhb = (unsigned short*)(ws + (4u << 20));    //  8 MB
    unsigned short* xb   = (unsigned short*)(ws + (12u << 20));   // 32 MB
    float*          bias = (float*)(ws + (46u << 20));            // 16 KB
    int*            arr  = (int*)(ws + (47u << 20));              // 32 KB
    unsigned short* hbs  = (unsigned short*)(ws + (48u << 20));   // 64 MB rotation

    zero_arr<<<32, 256, 0, stream>>>(arr, 64 * 128);
    cast_f32_to_bf16<<<1024, 256, 0, stream>>>(Wih, Wihb, (4 * HSZ * ISZ) / 8);
    cast_f32_to_bf16<<<2048, 256, 0, stream>>>(Whh, Whhb, (4 * HSZ * HSZ) / 8);
    cast_f32_to_bf16<<<8192, 256, 0, stream>>>(input_, xb, (TT * BSZ * ISZ) / 8);
    bias_combine<<<16, 256, 0, stream>>>(bih, bhh, bias);

    float* out = (float*)d_out;
    lstm_persist<<<256, 256, 0, stream>>>(xb, Wihb, Whhb, bias, out, hbs, arr);
}

// Round 10
// 1791.308 us; speedup vs baseline: 1.0602x; 1.0602x over previous
//
#include <hip/hip_runtime.h>

#define TT  64
#define BSZ 512
#define ISZ 512
#define HSZ 1024

typedef short bf16x8 __attribute__((ext_vector_type(8)));
typedef float f32x4 __attribute__((ext_vector_type(4)));
typedef unsigned short u16x8 __attribute__((ext_vector_type(8)));

typedef const __attribute__((address_space(1))) unsigned int* gas_t;
typedef __attribute__((address_space(3))) unsigned int* las_t;

__device__ __forceinline__ unsigned short f2bf(float f) {
    unsigned int u = __float_as_uint(f);
    unsigned int r = u + 0x7FFFu + ((u >> 16) & 1u);   // RNE
    return (unsigned short)(r >> 16);
}

__global__ void cast_f32_to_bf16(const float* __restrict__ in,
                                 unsigned short* __restrict__ out, int n8) {
    int i = blockIdx.x * blockDim.x + threadIdx.x;
    if (i >= n8) return;
    const float4* p = (const float4*)(in + (size_t)i * 8);
    float4 v0 = p[0], v1 = p[1];
    u16x8 o;
    o[0] = f2bf(v0.x); o[1] = f2bf(v0.y); o[2] = f2bf(v0.z); o[3] = f2bf(v0.w);
    o[4] = f2bf(v1.x); o[5] = f2bf(v1.y); o[6] = f2bf(v1.z); o[7] = f2bf(v1.w);
    *(u16x8*)(out + (size_t)i * 8) = o;
}

__global__ void bias_combine(const float* __restrict__ a,
                             const float* __restrict__ b,
                             float* __restrict__ o) {
    int i = blockIdx.x * blockDim.x + threadIdx.x;
    if (i < 4 * HSZ) o[i] = a[i] + b[i];
}

__global__ void zero_arr(int* p, int n) {
    int i = blockIdx.x * blockDim.x + threadIdx.x;
    if (i < n) p[i] = 0;
}

// Persistent LSTM, dataflow-synchronized (NO per-step barrier).
// 256 blocks (1/CU via 144KB LDS), 512 threads = 8 waves (2/SIMD).
// Waves: mg = wv&3 (32 b-rows), ks = wv>>2 (K half). W_hh slice (64x1024)
// LDS-resident. h rotates through 64 per-step buffers [ni'][512][16].
// Readiness: flags[t][mi][ni'] (one producer block each). Consumers poll
// only the 4 flags per 64-k superchunk, starting at their OWN columns
// (self-produced), with flag prefetch one superchunk ahead.
__global__ __launch_bounds__(512, 2) void lstm_persist(
    const unsigned short* __restrict__ xb,    // [TT, BSZ, ISZ] bf16
    const unsigned short* __restrict__ Wihb,  // [4096, 512]
    const unsigned short* __restrict__ Whhb,  // [4096, 1024]
    const float* __restrict__ bias,           // [4096]
    float* __restrict__ out,                  // fp32 output
    unsigned short* __restrict__ hbs,         // [TT][64][512][16] rotation
    int* __restrict__ flags)                  // [TT][4][64]
{
    __shared__ unsigned short WhL[64 * 1024];   // 128 KiB persistent W_hh
    __shared__ float WS[4096];                  //  16 KiB k-reduce

    const int tid  = threadIdx.x;
    const int lane = tid & 63;
    const int wv   = tid >> 6;       // 0..7
    const int mg   = wv & 3;         // 32-row group
    const int ks   = wv >> 2;        // K half (0,1)
    const int lr   = lane & 15;
    const int kq   = lane >> 4;      // 0..3
    const int mi   = blockIdx.x >> 6;
    const int ni   = blockIdx.x & 63;
    const int b0   = mi * 128;
    const int hc0  = ni * 16;

    // ---- stage persistent W_hh slice (async). LDS[r][slot u] = G[r][u^(r&7)] ----
    #pragma unroll
    for (int i = 0; i < 16; ++i) {
        const int li = wv * 16 + i;            // 1KB unit, 0..127
        const int r = li >> 1, half = li & 1;
        const int grow = (r >> 4) * HSZ + hc0 + (r & 15);
        const int gslot = (half * 64 + lane) ^ (r & 7);
        const unsigned short* g = Whhb + (size_t)grow * HSZ + (size_t)gslot * 8;
        __builtin_amdgcn_global_load_lds((gas_t)g, (las_t)(WhL + li * 512), 16, 0, 0);
    }

    float bv[4];
    #pragma unroll
    for (int g = 0; g < 4; ++g) bv[g] = bias[g * HSZ + hc0 + lr];

    // ---- x-projection (K half, direct global) ----
    auto x_part = [&](const unsigned short* xt, f32x4 (&acc)[2][4]) {
        #pragma unroll
        for (int m = 0; m < 2; ++m)
            #pragma unroll
            for (int g = 0; g < 4; ++g)
                acc[m][g] = (ks == 0) ? (f32x4){bv[g], bv[g], bv[g], bv[g]}
                                      : (f32x4){0.f, 0.f, 0.f, 0.f};
        const unsigned short* xr = xt + (size_t)(b0 + mg * 32 + lr) * ISZ + ks * 256 + kq * 8;
        const unsigned short* wr = Wihb + (size_t)(hc0 + lr) * ISZ + ks * 256 + kq * 8;
        bf16x8 ax[2][8];
        #pragma unroll
        for (int c = 0; c < 8; ++c) {
            ax[0][c] = *(const bf16x8*)(xr + c * 32);
            ax[1][c] = *(const bf16x8*)(xr + 16 * ISZ + c * 32);
        }
        #pragma unroll
        for (int c = 0; c < 8; ++c) {
            #pragma unroll
            for (int g = 0; g < 4; ++g) {
                bf16x8 wf = *(const bf16x8*)(wr + (size_t)g * HSZ * ISZ + c * 32);
                acc[0][g] = __builtin_amdgcn_mfma_f32_16x16x32_bf16(ax[0][c], wf, acc[0][g], 0, 0, 0);
                acc[1][g] = __builtin_amdgcn_mfma_f32_16x16x32_bf16(ax[1][c], wf, acc[1][g], 0, 0, 0);
            }
        }
    };

    // ---- recurrent half-GEMM, flag-paced superchunks of 64k ----
    auto flagsum = [&](const int* fp) {
        return __hip_atomic_load(fp + 0, __ATOMIC_RELAXED, __HIP_MEMORY_SCOPE_AGENT)
             + __hip_atomic_load(fp + 1, __ATOMIC_RELAXED, __HIP_MEMORY_SCOPE_AGENT)
             + __hip_atomic_load(fp + 2, __ATOMIC_RELAXED, __HIP_MEMORY_SCOPE_AGENT)
             + __hip_atomic_load(fp + 3, __ATOMIC_RELAXED, __HIP_MEMORY_SCOPE_AGENT);
    };

    auto h_gemm = [&](const unsigned short* hp, const int* fl, f32x4 (&acc)[2][4]) {
        const int br0 = b0 + mg * 32 + lr;
        const int s0 = ((ni >> 2) - (ks << 3)) & 7;

        auto lda4 = [&](int s, bf16x8 (&a)[2][2]) {
            const int k0 = (ks << 9) + (s << 6);
            #pragma unroll
            for (int cc = 0; cc < 2; ++cc) {
                const int kc = k0 + cc * 32 + kq * 8;
                const size_t base = (size_t)(kc >> 4) * 8192 + (kc & 15);
                a[0][cc] = *(const bf16x8*)(hp + base + (size_t)br0 * 16);
                a[1][cc] = *(const bf16x8*)(hp + base + (size_t)(br0 + 16) * 16);
            }
        };
        auto mfma8 = [&](int s, int cc, bf16x8 a0, bf16x8 a1) {
            const int c = (ks << 4) + (s << 1) + cc;          // global k32 chunk
            const int woff = ((c * 4 + kq) ^ (lr & 7)) << 4;
            #pragma unroll
            for (int g = 0; g < 4; ++g) {
                bf16x8 wf = *(const bf16x8*)((const char*)WhL + (g * 16 + lr) * 2048 + woff);
                acc[0][g] = __builtin_amdgcn_mfma_f32_16x16x32_bf16(a0, wf, acc[0][g], 0, 0, 0);
                acc[1][g] = __builtin_amdgcn_mfma_f32_16x16x32_bf16(a1, wf, acc[1][g], 0, 0, 0);
            }
        };

        bf16x8 aA[2][2], aB[2][2];
        // first superchunk: own columns (self-produced) — spin should be ~0
        {
            const int* fp = fl + (ks << 5) + (s0 << 2);
            int c = flagsum(fp);
            while (c < 4) { __builtin_amdgcn_s_sleep(1); c = flagsum(fp); }
            asm volatile("" ::: "memory");
        }
        lda4(s0, aA);
        int pf = (8 > 7) ? 4 : 0;  // placeholder
        {
            const int s1 = (s0 + 1) & 7;
            pf = flagsum(fl + (ks << 5) + (s1 << 2));   // prefetch flags for s1
        }

        #pragma unroll
        for (int jj = 0; jj < 8; ++jj) {
            const int s  = (s0 + jj) & 7;
            const int sn = (s0 + jj + 1) & 7;
            if ((jj & 1) == 0) {
                mfma8(s, 0, aA[0][0], aA[1][0]);
                if (jj < 7) {
                    if (pf < 4) {
                        const int* fp = fl + (ks << 5) + (sn << 2);
                        do { __builtin_amdgcn_s_sleep(1); pf = flagsum(fp); } while (pf < 4);
                    }
                    asm volatile("" ::: "memory");
                    lda4(sn, aB);
                    if (jj < 6) pf = flagsum(fl + (ks << 5) + (((s0 + jj + 2) & 7) << 2));
                }
                mfma8(s, 1, aA[0][1], aA[1][1]);
            } else {
                mfma8(s, 0, aB[0][0], aB[1][0]);
                if (jj < 7) {
                    if (pf < 4) {
                        const int* fp = fl + (ks << 5) + (sn << 2);
                        do { __builtin_amdgcn_s_sleep(1); pf = flagsum(fp); } while (pf < 4);
                    }
                    asm volatile("" ::: "memory");
                    lda4(sn, aA);
                    if (jj < 6) pf = flagsum(fl + (ks << 5) + (((s0 + jj + 2) & 7) << 2));
                }
                mfma8(s, 1, aB[0][1], aB[1][1]);
            }
        }
    };

    f32x4 acc[2][4];
    f32x4 creg[2];
    creg[0] = (f32x4){0.f, 0.f, 0.f, 0.f};
    creg[1] = (f32x4){0.f, 0.f, 0.f, 0.f};

    x_part(xb, acc);                                   // acc for t=0
    asm volatile("s_waitcnt vmcnt(0)" ::: "memory");   // W_hh staged
    __syncthreads();

    float* hn = out + (size_t)TT * BSZ * HSZ;
    float* cn = hn + (size_t)BSZ * HSZ;
    const int n = hc0 + lr;

    for (int t = 0; t < TT; ++t) {
        if (t > 0)
            h_gemm(hbs + (size_t)(t - 1) * 524288,
                   flags + ((size_t)(t - 1) * 4 + mi) * 64, acc);

        // ---- merge K halves: ks=1 -> ks=0 (2 m-rounds, 16KB, lane-contig) ----
        #pragma unroll
        for (int m = 0; m < 2; ++m) {
            if (ks == 1) {
                #pragma unroll
                for (int g = 0; g < 4; ++g)
                    *(f32x4*)&WS[mg * 1024 + g * 256 + lane * 4] = acc[m][g];
            }
            __syncthreads();
            if (ks == 0) {
                #pragma unroll
                for (int g = 0; g < 4; ++g)
                    acc[m][g] += *(const f32x4*)&WS[mg * 1024 + g * 256 + lane * 4];
            }
            __syncthreads();
        }

        // ---- LSTM pointwise epilogue (ks==0 waves own full gates) ----
        f32x4 hv[2];
        if (ks == 0) {
            unsigned short* hslab = hbs + (size_t)t * 524288 + (size_t)ni * 8192;
            #pragma unroll
            for (int m = 0; m < 2; ++m) {
                #pragma unroll
                for (int r = 0; r < 4; ++r) {
                    const int b = b0 + mg * 32 + m * 16 + kq * 4 + r;
                    float gi = acc[m][0][r];
                    float gf = acc[m][1][r];
                    float gg = acc[m][2][r];
                    float go = acc[m][3][r];
                    float ig = 1.f / (1.f + __expf(-gi));
                    float fg = 1.f / (1.f + __expf(-gf));
                    float gv = 1.f - 2.f / (__expf(2.f * gg) + 1.f);
                    float og = 1.f / (1.f + __expf(-go));
                    float cnew = fg * creg[m][r] + ig * gv;
                    float h = og * (1.f - 2.f / (__expf(2.f * cnew) + 1.f));
                    creg[m][r] = cnew;
                    hv[m][r] = h;
                    hslab[(size_t)b * 16 + lr] = f2bf(h);
                }
            }
        }
        __syncthreads();   // all hbn stores drained (per-wave vmcnt0 at barrier)

        float* outt = out + (size_t)t * BSZ * HSZ;
        if (t + 1 < TT) {
            if (tid == 0)
                __hip_atomic_store(flags + ((size_t)t * 4 + mi) * 64 + ni, 1,
                                   __ATOMIC_RELEASE, __HIP_MEMORY_SCOPE_AGENT);
            if (ks == 0) {
                #pragma unroll
                for (int m = 0; m < 2; ++m)
                    #pragma unroll
                    for (int r = 0; r < 4; ++r) {
                        const int b = b0 + mg * 32 + m * 16 + kq * 4 + r;
                        outt[(size_t)b * HSZ + n] = hv[m][r];
                    }
            }
            x_part(xb + (size_t)(t + 1) * BSZ * ISZ, acc);   // gives producers slack
        } else {
            if (ks == 0) {
                #pragma unroll
                for (int m = 0; m < 2; ++m)
                    #pragma unroll
                    for (int r = 0; r < 4; ++r) {
                        const int b = b0 + mg * 32 + m * 16 + kq * 4 + r;
                        const size_t idx = (size_t)b * HSZ + n;
                        outt[idx] = hv[m][r];
                        hn[idx] = hv[m][r];
                        cn[idx] = creg[m][r];
                    }
            }
        }
    }
}

extern "C" void kernel_launch(void* const* d_in, const int* in_sizes, int n_in,
                              void* d_out, int out_size, void* d_ws, size_t ws_size,
                              hipStream_t stream) {
    const float* input_ = (const float*)d_in[0];
    const float* Wih = (const float*)d_in[3];
    const float* Whh = (const float*)d_in[4];
    const float* bih = (const float*)d_in[5];
    const float* bhh = (const float*)d_in[6];

    char* ws = (char*)d_ws;
    unsigned short* Wihb = (unsigned short*)(ws);                 //  4 MB
    unsigned short* Whhb = (unsigned short*)(ws + (4u << 20));    //  8 MB
    unsigned short* xb   = (unsigned short*)(ws + (12u << 20));   // 32 MB
    float*          bias = (float*)(ws + (46u << 20));            // 16 KB
    int*            flg  = (int*)(ws + (47u << 20));              // 64 KB
    unsigned short* hbs  = (unsigned short*)(ws + (48u << 20));   // 64 MB rotation

    zero_arr<<<64, 256, 0, stream>>>(flg, TT * 4 * 64);
    cast_f32_to_bf16<<<1024, 256, 0, stream>>>(Wih, Wihb, (4 * HSZ * ISZ) / 8);
    cast_f32_to_bf16<<<2048, 256, 0, stream>>>(Whh, Whhb, (4 * HSZ * HSZ) / 8);
    cast_f32_to_bf16<<<8192, 256, 0, stream>>>(input_, xb, (TT * BSZ * ISZ) / 8);
    bias_combine<<<16, 256, 0, stream>>>(bih, bhh, bias);

    float* out = (float*)d_out;
    lstm_persist<<<256, 512, 0, stream>>>(xb, Wihb, Whhb, bias, out, hbs, flg);
}

// Round 11
// 1359.280 us; speedup vs baseline: 1.3972x; 1.3178x over previous
//
#include <hip/hip_runtime.h>

#define TT  64
#define BSZ 512
#define ISZ 512
#define HSZ 1024

typedef short bf16x8 __attribute__((ext_vector_type(8)));
typedef float f32x4 __attribute__((ext_vector_type(4)));
typedef unsigned short u16x8 __attribute__((ext_vector_type(8)));

typedef const __attribute__((address_space(1))) unsigned int* gas_t;
typedef __attribute__((address_space(3))) unsigned int* las_t;

__device__ __forceinline__ unsigned short f2bf(float f) {
    unsigned int u = __float_as_uint(f);
    unsigned int r = u + 0x7FFFu + ((u >> 16) & 1u);   // RNE
    return (unsigned short)(r >> 16);
}
__device__ __forceinline__ float bf2f(unsigned short u) {
    return __uint_as_float(((unsigned int)u) << 16);
}

__global__ void cast_f32_to_bf16(const float* __restrict__ in,
                                 unsigned short* __restrict__ out, int n8) {
    int i = blockIdx.x * blockDim.x + threadIdx.x;
    if (i >= n8) return;
    const float4* p = (const float4*)(in + (size_t)i * 8);
    float4 v0 = p[0], v1 = p[1];
    u16x8 o;
    o[0] = f2bf(v0.x); o[1] = f2bf(v0.y); o[2] = f2bf(v0.z); o[3] = f2bf(v0.w);
    o[4] = f2bf(v1.x); o[5] = f2bf(v1.y); o[6] = f2bf(v1.z); o[7] = f2bf(v1.w);
    *(u16x8*)(out + (size_t)i * 8) = o;
}

__global__ void bias_combine(const float* __restrict__ a,
                             const float* __restrict__ b,
                             float* __restrict__ o) {
    int i = blockIdx.x * blockDim.x + threadIdx.x;
    if (i < 4 * HSZ) o[i] = a[i] + b[i];
}

__global__ void zero_arr(int* p, int n) {
    int i = blockIdx.x * blockDim.x + threadIdx.x;
    if (i < n) p[i] = 0;
}

// ---------------- Phase 1: XG[t] = x_t @ Wih^T + bias  (bf16 out) ----------
// 8192 blocks = 64 t x (4 mi x 32 h-tiles of 32 cols). R3's proven x-block
// structure: 128b x (4g x 32h) tile, 4 waves m4n4, LDS dbuf, vmcnt(8).
__global__ __launch_bounds__(256) void xg_gemm(
    const unsigned short* __restrict__ xb,    // [TT,512,512] bf16
    const unsigned short* __restrict__ Wihb,  // [4096,512] bf16
    const float* __restrict__ bias,           // [4096]
    unsigned short* __restrict__ XG)          // [TT,512,4096] bf16
{
    __shared__ unsigned short Ab[2][128 * 64];
    __shared__ unsigned short Wb[2][128 * 64];

    const int t   = blockIdx.x >> 7;
    const int j   = blockIdx.x & 127;
    const int xcd = j & 7;
    const int idx = j >> 3;
    const int hh0 = (xcd * 4 + (idx & 3)) * 32;
    const int bb0 = (idx >> 2) * 128;

    const unsigned short* A = xb + (size_t)t * BSZ * ISZ;

    const int lane = threadIdx.x & 63;
    const int wv   = threadIdx.x >> 6;
    const int wx   = wv & 1;
    const int wy   = wv >> 1;
    const int lr   = lane & 15;
    const int kq   = lane >> 4;

    const f32x4 z = {0.f, 0.f, 0.f, 0.f};
    f32x4 acc[4][4];
    #pragma unroll
    for (int m = 0; m < 4; ++m)
        #pragma unroll
        for (int g = 0; g < 4; ++g) acc[m][g] = z;

    auto stage = [&](int k0, unsigned short* Abuf, unsigned short* Wbuf) {
        const int sub = lane >> 3;
        const int swk = ((lane & 7) ^ sub) * 8;
        #pragma unroll
        for (int i = 0; i < 4; ++i) {
            const int tr8 = (wv * 4 + i) * 8;
            const unsigned short* g = A + (size_t)(bb0 + tr8 + sub) * ISZ + k0 + swk;
            __builtin_amdgcn_global_load_lds((gas_t)g, (las_t)(Abuf + tr8 * 64), 16, 0, 0);
        }
        #pragma unroll
        for (int i = 0; i < 4; ++i) {
            const int tr8 = (wv * 4 + i) * 8;
            const int tr = tr8 + sub;
            const int wrow = hh0 + (tr & 31) + (tr >> 5) * 1024;
            const unsigned short* g = Wihb + (size_t)wrow * ISZ + k0 + swk;
            __builtin_amdgcn_global_load_lds((gas_t)g, (las_t)(Wbuf + tr8 * 64), 16, 0, 0);
        }
    };

    stage(0, Ab[0], Wb[0]);
    const int swz = (lr & 7) << 4;
    for (int c = 0; c < 8; ++c) {
        const int buf = c & 1;
        if (c + 1 < 8) {
            stage((c + 1) * 64, Ab[buf ^ 1], Wb[buf ^ 1]);
            asm volatile("s_waitcnt vmcnt(8)" ::: "memory");
        } else {
            asm volatile("s_waitcnt vmcnt(0)" ::: "memory");
        }
        __builtin_amdgcn_sched_barrier(0);
        __builtin_amdgcn_s_barrier();

        const char* Ac = (const char*)Ab[buf];
        const char* Wc = (const char*)Wb[buf];
        #pragma unroll
        for (int ks = 0; ks < 2; ++ks) {
            const int kb = ks * 64 + kq * 16;
            bf16x8 wf[4], af[4];
            #pragma unroll
            for (int g = 0; g < 4; ++g) {
                const int tr = g * 32 + wx * 16 + lr;
                wf[g] = *(const bf16x8*)(Wc + tr * 128 + (kb ^ swz));
            }
            #pragma unroll
            for (int m = 0; m < 4; ++m) {
                const int tr = wy * 64 + m * 16 + lr;
                af[m] = *(const bf16x8*)(Ac + tr * 128 + (kb ^ swz));
            }
            #pragma unroll
            for (int m = 0; m < 4; ++m)
                #pragma unroll
                for (int g = 0; g < 4; ++g)
                    acc[m][g] = __builtin_amdgcn_mfma_f32_16x16x32_bf16(af[m], wf[g], acc[m][g], 0, 0, 0);
        }
        __builtin_amdgcn_s_barrier();
    }

    const int n = hh0 + wx * 16 + lr;
    float bv[4];
    #pragma unroll
    for (int g = 0; g < 4; ++g) bv[g] = bias[g * HSZ + n];
    unsigned short* XGp = XG + (size_t)t * BSZ * (4 * HSZ);
    #pragma unroll
    for (int m = 0; m < 4; ++m) {
        #pragma unroll
        for (int r = 0; r < 4; ++r) {
            const int b = bb0 + wy * 64 + m * 16 + kq * 4 + r;
            #pragma unroll
            for (int g = 0; g < 4; ++g)
                XGp[(size_t)b * (4 * HSZ) + g * HSZ + n] = f2bf(acc[m][g][r] + bv[g]);
        }
    }
}

// ---------------- Phase 2: recurrence only ---------------------------------
// 256 blocks (1/CU via 144KB LDS), 512 thr = 8 waves (2/SIMD).
// mg = wv&3 (32 b-rows), ks = wv>>2 (K half). W_hh slice LDS-resident.
// 3-barrier ks-exchange; epilogue split across ALL 8 waves (each owns m=ks).
// xg prefetched one step ahead into registers (static data).
// h rotates through 64 per-step buffers [ni'][512][16] (R7 coherence scheme).
__global__ __launch_bounds__(512, 2) void lstm_rec(
    const unsigned short* __restrict__ XG,    // [TT,512,4096] bf16
    const unsigned short* __restrict__ Whhb,  // [4096,1024] bf16
    float* __restrict__ out,
    unsigned short* __restrict__ hbs,         // [TT][64][512][16]
    int* __restrict__ arrive)
{
    __shared__ unsigned short WhL[64 * 1024];   // 128 KiB persistent W_hh
    __shared__ float WS[4096];                  //  16 KiB exchange

    const int tid  = threadIdx.x;
    const int lane = tid & 63;
    const int wv   = tid >> 6;
    const int mg   = wv & 3;
    const int ks   = wv >> 2;
    const int lr   = lane & 15;
    const int kq   = lane >> 4;
    const int mi   = blockIdx.x >> 6;
    const int ni   = blockIdx.x & 63;
    const int b0   = mi * 128;
    const int hc0  = ni * 16;

    // ---- stage persistent W_hh slice. LDS[r][slot u] = G[r][u^(r&7)] ----
    #pragma unroll
    for (int i = 0; i < 16; ++i) {
        const int li = wv * 16 + i;
        const int r = li >> 1, half = li & 1;
        const int grow = (r >> 4) * HSZ + hc0 + (r & 15);
        const int gslot = (half * 64 + lane) ^ (r & 7);
        const unsigned short* g = Whhb + (size_t)grow * HSZ + (size_t)gslot * 8;
        __builtin_amdgcn_global_load_lds((gas_t)g, (las_t)(WhL + li * 512), 16, 0, 0);
    }

    const int bth = b0 + mg * 32 + ks * 16 + kq * 4;   // this thread's 4 rows
    const int n   = hc0 + lr;
    const unsigned short* xgp = XG + (size_t)bth * (4 * HSZ) + n;

    unsigned short xgc[16];
    #pragma unroll
    for (int g = 0; g < 4; ++g)
        #pragma unroll
        for (int r = 0; r < 4; ++r)
            xgc[g * 4 + r] = xgp[(size_t)r * (4 * HSZ) + g * HSZ];   // t=0

    auto h_gemm = [&](const unsigned short* hp, f32x4 (&acc)[2][4]) {
        const int br0 = b0 + mg * 32 + lr;
        #pragma unroll
        for (int half = 0; half < 2; ++half) {
            bf16x8 a[2][8];
            #pragma unroll
            for (int c8 = 0; c8 < 8; ++c8) {
                const int c = half * 8 + c8;
                const int kc = ks * 512 + c * 32 + kq * 8;
                const size_t base = (size_t)(kc >> 4) * 8192 + (kc & 15);
                a[0][c8] = *(const bf16x8*)(hp + base + (size_t)br0 * 16);
                a[1][c8] = *(const bf16x8*)(hp + base + (size_t)(br0 + 16) * 16);
            }
            #pragma unroll
            for (int c8 = 0; c8 < 8; ++c8) {
                const int c = half * 8 + c8;
                const int u0 = ks * 64 + c * 4 + kq;
                const int woff = ((u0 ^ (lr & 7)) << 4);
                #pragma unroll
                for (int g = 0; g < 4; ++g) {
                    bf16x8 wf = *(const bf16x8*)((const char*)WhL + (g * 16 + lr) * 2048 + woff);
                    acc[0][g] = __builtin_amdgcn_mfma_f32_16x16x32_bf16(a[0][c8], wf, acc[0][g], 0, 0, 0);
                    acc[1][g] = __builtin_amdgcn_mfma_f32_16x16x32_bf16(a[1][c8], wf, acc[1][g], 0, 0, 0);
                }
            }
        }
    };

    asm volatile("s_waitcnt vmcnt(0)" ::: "memory");   // W_hh + xg(0) ready
    __syncthreads();

    float* hn = out + (size_t)TT * BSZ * HSZ;
    float* cn = hn + (size_t)BSZ * HSZ;
    f32x4 creg = {0.f, 0.f, 0.f, 0.f};

    for (int t = 0; t < TT; ++t) {
        f32x4 accf[4];
        if (t > 0) {
            const f32x4 z = {0.f, 0.f, 0.f, 0.f};
            f32x4 acc[2][4];
            #pragma unroll
            for (int m = 0; m < 2; ++m)
                #pragma unroll
                for (int g = 0; g < 4; ++g) acc[m][g] = z;
            h_gemm(hbs + (size_t)(t - 1) * 524288, acc);

            // ---- 3-barrier exchange: wave finalizes m == ks ----
            if (ks == 1) {
                #pragma unroll
                for (int g = 0; g < 4; ++g)
                    *(f32x4*)&WS[mg * 1024 + g * 256 + lane * 4] = acc[0][g];
            }
            __syncthreads();
            if (ks == 0) {
                #pragma unroll
                for (int g = 0; g < 4; ++g)
                    accf[g] = acc[0][g] + *(const f32x4*)&WS[mg * 1024 + g * 256 + lane * 4];
            }
            __syncthreads();
            if (ks == 0) {
                #pragma unroll
                for (int g = 0; g < 4; ++g)
                    *(f32x4*)&WS[mg * 1024 + g * 256 + lane * 4] = acc[1][g];
            }
            __syncthreads();
            if (ks == 1) {
                #pragma unroll
                for (int g = 0; g < 4; ++g)
                    accf[g] = acc[1][g] + *(const f32x4*)&WS[mg * 1024 + g * 256 + lane * 4];
            }
        } else {
            #pragma unroll
            for (int g = 0; g < 4; ++g) accf[g] = (f32x4){0.f, 0.f, 0.f, 0.f};
        }

        // ---- LSTM pointwise (all 8 waves; each owns rows bth..bth+3) ----
        unsigned short* hslab = hbs + (size_t)t * 524288 + (size_t)ni * 8192;
        float hv[4];
        #pragma unroll
        for (int r = 0; r < 4; ++r) {
            float gi = accf[0][r] + bf2f(xgc[0 * 4 + r]);
            float gf = accf[1][r] + bf2f(xgc[1 * 4 + r]);
            float gg = accf[2][r] + bf2f(xgc[2 * 4 + r]);
            float go = accf[3][r] + bf2f(xgc[3 * 4 + r]);
            float ig = 1.f / (1.f + __expf(-gi));
            float fg = 1.f / (1.f + __expf(-gf));
            float gv = 1.f - 2.f / (__expf(2.f * gg) + 1.f);
            float og = 1.f / (1.f + __expf(-go));
            float cnew = fg * creg[r] + ig * gv;
            float h = og * (1.f - 2.f / (__expf(2.f * cnew) + 1.f));
            creg[r] = cnew;
            hv[r] = h;
            hslab[(size_t)(bth + r) * 16 + lr] = f2bf(h);
        }
        __syncthreads();   // drain hslab stores; protect WS for next step

        float* outt = out + (size_t)t * BSZ * HSZ;
        if (t + 1 < TT) {
            int* ctr = arrive + (size_t)t * 128 + mi * 32;
            if (tid == 0)
                __hip_atomic_fetch_add(ctr, 1, __ATOMIC_RELEASE, __HIP_MEMORY_SCOPE_AGENT);
            // spin filler: deferred out stores + xg(t+1) prefetch
            #pragma unroll
            for (int r = 0; r < 4; ++r)
                outt[(size_t)(bth + r) * HSZ + n] = hv[r];
            const unsigned short* xgn = xgp + (size_t)(t + 1) * BSZ * (4 * HSZ);
            #pragma unroll
            for (int g = 0; g < 4; ++g)
                #pragma unroll
                for (int r = 0; r < 4; ++r)
                    xgc[g * 4 + r] = xgn[(size_t)r * (4 * HSZ) + g * HSZ];
            if (tid == 0) {
                while (__hip_atomic_load(ctr, __ATOMIC_RELAXED, __HIP_MEMORY_SCOPE_AGENT) < 64)
                    __builtin_amdgcn_s_sleep(1);
            }
            __syncthreads();
        } else {
            #pragma unroll
            for (int r = 0; r < 4; ++r) {
                const size_t idx = (size_t)(bth + r) * HSZ + n;
                outt[idx] = hv[r];
                hn[idx] = hv[r];
                cn[idx] = creg[r];
            }
        }
    }
}

extern "C" void kernel_launch(void* const* d_in, const int* in_sizes, int n_in,
                              void* d_out, int out_size, void* d_ws, size_t ws_size,
                              hipStream_t stream) {
    const float* input_ = (const float*)d_in[0];
    const float* Wih = (const float*)d_in[3];
    const float* Whh = (const float*)d_in[4];
    const float* bih = (const float*)d_in[5];
    const float* bhh = (const float*)d_in[6];

    char* ws = (char*)d_ws;
    unsigned short* Wihb = (unsigned short*)(ws);                  //   4 MB
    unsigned short* Whhb = (unsigned short*)(ws + (4u << 20));     //   8 MB
    unsigned short* xb   = (unsigned short*)(ws + (12u << 20));    //  32 MB
    float*          bias = (float*)(ws + (44u << 20));             //  16 KB
    int*            arr  = (int*)(ws + (45u << 20));               //  32 KB
    unsigned short* hbs  = (unsigned short*)(ws + (46u << 20));    //  64 MB
    unsigned short* XG   = (unsigned short*)(ws + (110u << 20));   // 256 MB

    zero_arr<<<32, 256, 0, stream>>>(arr, TT * 128);
    cast_f32_to_bf16<<<1024, 256, 0, stream>>>(Wih, Wihb, (4 * HSZ * ISZ) / 8);
    cast_f32_to_bf16<<<2048, 256, 0, stream>>>(Whh, Whhb, (4 * HSZ * HSZ) / 8);
    cast_f32_to_bf16<<<8192, 256, 0, stream>>>(input_, xb, (TT * BSZ * ISZ) / 8);
    bias_combine<<<16, 256, 0, stream>>>(bih, bhh, bias);

    float* out = (float*)d_out;
    xg_gemm<<<TT * 128, 256, 0, stream>>>(xb, Wihb, bias, XG);
    lstm_rec<<<256, 512, 0, stream>>>(XG, Whhb, out, hbs, arr);
}